// Round 5
// baseline (199.713 us; speedup 1.0000x reference)
//
#include <hip/hip_runtime.h>
#include <math.h>

// SimpleSplitFF: sparse expert-choice MoE.
// x:(4,4096,1024) f32, controller:(1024,32), f1:(1024,32,128), bias:(32,128), f2:(32,128,1024)
// perm is one-hot over g per (b,t,e) scaled by softmax-over-g prob -> only 512 routed rows.

#define DM   1024
#define NE   32
#define FE   128
#define T4   4
#define SS   4096
#define NGRP 1024
#define NROW 512                       // route rows r = (b*4+t)*32+e = row16*32+e
#define LP_STRIDE (NROW * NGRP)        // one K-split partial (2 MiB)
#define VP_OFF   524288                // Vp partials: aliases Lp splits 1-2 (dead after route)

// ---------------------------------------------------------------------------
// K1: partial logits Lp[ks][row][g] + fused zeroing of d_out.
// grid (128,4) = 512 blocks. Tile 128 tok x 32 e, thread 4tok x 4e (16 FMA
// per 2 ds_read_b128). Register-prefetch double buffer overlaps next kit's
// global loads with current compute.
// ---------------------------------------------------------------------------
__global__ __launch_bounds__(256, 2)
void k_logits(const float* __restrict__ x, const float* __restrict__ ctrl,
              float* __restrict__ Lp, float* __restrict__ out)
{
    const int m      = blockIdx.x;
    const int ks     = blockIdx.y;
    const int tid    = threadIdx.x;
    const int base_s = m * 128;                // never straddles b (128 | 4096)
    const int b      = base_s >> 12;
    const int g0     = (base_s & 4095) >> 2;

    __shared__ float xT[64 * 132];   // [d][tok], pad 132
    __shared__ float cs[64 * 32];    // [d][e]

    const int tq = tid & 31;         // token quad (group)
    const int eg = tid >> 5;         // 0..7 -> experts eg*4..+3

    float acc[4][4];
#pragma unroll
    for (int i = 0; i < 4; ++i)
#pragma unroll
        for (int j = 0; j < 4; ++j) acc[i][j] = 0.f;

    const int row0 = tid >> 2;       // staging token row 0..63 (+64)
    const int f4i  = tid & 3;

    float4 px[2][4];                 // prefetch: x rows {row0, row0+64} x 4 cols
    float4 pc[2];                    // prefetch: ctrl 2 float4

    {   // preload kit 0
        const int k0 = ks * 256;
#pragma unroll
        for (int rr = 0; rr < 2; ++rr) {
            const float* xp = x + (size_t)(base_s + row0 + rr * 64) * DM + k0;
#pragma unroll
            for (int cr = 0; cr < 4; ++cr)
                px[rr][cr] = *(const float4*)(xp + (f4i + cr * 4) * 4);
        }
        const float4* cg = (const float4*)(ctrl + (size_t)k0 * NE);
        pc[0] = cg[tid]; pc[1] = cg[tid + 256];
    }

    for (int kit = 0; kit < 4; ++kit) {
        __syncthreads();             // previous compute done
        // store prefetched tile to LDS (transposed x)
#pragma unroll
        for (int rr = 0; rr < 2; ++rr) {
            const int row = row0 + rr * 64;
#pragma unroll
            for (int cr = 0; cr < 4; ++cr) {
                const int d = (f4i + cr * 4) * 4;
                const float4 v = px[rr][cr];
                xT[(d + 0) * 132 + row] = v.x;
                xT[(d + 1) * 132 + row] = v.y;
                xT[(d + 2) * 132 + row] = v.z;
                xT[(d + 3) * 132 + row] = v.w;
            }
        }
        {
            float4* cl = (float4*)cs;
            cl[tid] = pc[0]; cl[tid + 256] = pc[1];
        }
        __syncthreads();             // staging visible

        if (kit < 3) {               // issue next kit's loads (overlap compute)
            const int k0 = ks * 256 + (kit + 1) * 64;
#pragma unroll
            for (int rr = 0; rr < 2; ++rr) {
                const float* xp = x + (size_t)(base_s + row0 + rr * 64) * DM + k0;
#pragma unroll
                for (int cr = 0; cr < 4; ++cr)
                    px[rr][cr] = *(const float4*)(xp + (f4i + cr * 4) * 4);
            }
            const float4* cg = (const float4*)(ctrl + (size_t)k0 * NE);
            pc[0] = cg[tid]; pc[1] = cg[tid + 256];
        }

#pragma unroll 4
        for (int d = 0; d < 64; ++d) {
            const float4 xv = *(const float4*)(xT + d * 132 + tq * 4);
            const float4 cv = *(const float4*)(cs + d * 32 + eg * 4);
            const float xa[4] = { xv.x, xv.y, xv.z, xv.w };
            const float ca[4] = { cv.x, cv.y, cv.z, cv.w };
#pragma unroll
            for (int i = 0; i < 4; ++i)
#pragma unroll
                for (int j = 0; j < 4; ++j) acc[i][j] += xa[i] * ca[j];
        }
    }

    {   // write partial logits
        float* Lb = Lp + (size_t)ks * LP_STRIDE;
        const int g = g0 + tq;
#pragma unroll
        for (int i = 0; i < 4; ++i)
#pragma unroll
            for (int j = 0; j < 4; ++j) {
                const int row = (b * T4 + i) * NE + eg * 4 + j;
                Lb[(size_t)row * NGRP + g] = acc[i][j];
            }
    }

    {   // fused zero: rows [base_s + ks*32, +32)
        const float4 z = make_float4(0.f, 0.f, 0.f, 0.f);
        float4* o4 = (float4*)(out + (size_t)(base_s + ks * 32) * DM);
#pragma unroll 4
        for (int i = tid; i < 32 * DM / 4; i += 256) o4[i] = z;
    }
}

// ---------------------------------------------------------------------------
// K2: route. grid 512 x 64 thr (one wave per row). Sums 4 K-partials, online
// softmax+argmax over g. Stores g (int bits) at Lp[row][0], p at Lp[row][1].
// ---------------------------------------------------------------------------
__global__ __launch_bounds__(64)
void k_route(float* __restrict__ Lp)
{
    const int r    = blockIdx.x;
    const int lane = threadIdx.x;
    const float* L0 = Lp + (size_t)r * NGRP;

    float mx = -INFINITY, s = 0.f;
    int gm = 0;
#pragma unroll
    for (int c = 0; c < 4; ++c) {
        const int g0c = c * 256 + lane * 4;
        const float4 v0 = *(const float4*)(L0 + g0c);
        const float4 v1 = *(const float4*)(L0 + 1 * LP_STRIDE + g0c);
        const float4 v2 = *(const float4*)(L0 + 2 * LP_STRIDE + g0c);
        const float4 v3 = *(const float4*)(L0 + 3 * LP_STRIDE + g0c);
        const float l[4] = { v0.x + v1.x + v2.x + v3.x,
                             v0.y + v1.y + v2.y + v3.y,
                             v0.z + v1.z + v2.z + v3.z,
                             v0.w + v1.w + v2.w + v3.w };
#pragma unroll
        for (int j = 0; j < 4; ++j) {
            const float lv = l[j];
            if (lv > mx) { s = s * __expf(mx - lv) + 1.f; mx = lv; gm = g0c + j; }
            else         { s += __expf(lv - mx); }
        }
    }
#pragma unroll
    for (int off = 1; off < 64; off <<= 1) {
        const float m2 = __shfl_xor(mx, off);
        const float s2 = __shfl_xor(s, off);
        const int   g2 = __shfl_xor(gm, off);
        const float mn = fmaxf(mx, m2);
        s  = s * __expf(mx - mn) + s2 * __expf(m2 - mn);
        gm = (m2 > mx) ? g2 : ((m2 == mx && g2 < gm) ? g2 : gm);
        mx = mn;
    }
    if (lane == 0) {
        ((int*)Lp)[(size_t)r * NGRP] = gm;
        Lp[(size_t)r * NGRP + 1] = 1.f / s;
    }
}

// ---------------------------------------------------------------------------
// K3: up-projection partials. grid 1024 = (rh 2)<<9 | (dc 16)<<5 | (e 32).
// Vp[dc][e][row16][f]. 1 row/thread, unroll-16 f1 stream.
// ---------------------------------------------------------------------------
__global__ __launch_bounds__(256, 4)
void k_up(const float* __restrict__ x, const float* __restrict__ f1,
          float* __restrict__ ws)
{
    const int e   = blockIdx.x & 31;
    const int dc  = (blockIdx.x >> 5) & 15;    // 64-d chunk
    const int rh  = blockIdx.x >> 9;           // rows rh*8..+7
    const int tid = threadIdx.x;

    __shared__ float xs[8 * 68];
    __shared__ int   gS[8];

    if (tid < 8) {
        const int r = (rh * 8 + tid) * NE + e;
        gS[tid] = ((const int*)ws)[(size_t)r * NGRP];
    }
    __syncthreads();

    if (tid < 128) {   // stage 8 rows x 64 d
        const int row = tid >> 4;
        const int f4c = tid & 15;
        const int grow = rh * 8 + row;
        const int bq = grow >> 2, t = grow & 3;
        const int s = bq * SS + gS[row] * 4 + t;
        const float4 v = *(const float4*)(x + (size_t)s * DM + dc * 64 + f4c * 4);
        xs[row * 68 + f4c * 4 + 0] = v.x;
        xs[row * 68 + f4c * 4 + 1] = v.y;
        xs[row * 68 + f4c * 4 + 2] = v.z;
        xs[row * 68 + f4c * 4 + 3] = v.w;
    }
    __syncthreads();

    const int f4 = tid & 31;                   // 4 f's
    const int rw = tid >> 5;                   // local row 0..7
    const float* f1p = f1 + (size_t)(dc * 64) * (NE * FE) + e * FE + f4 * 4;
    const float* xp  = xs + rw * 68;

    float a[4] = {0.f, 0.f, 0.f, 0.f};
#pragma unroll 16
    for (int dl = 0; dl < 64; ++dl) {
        const float4 w4 = *(const float4*)(f1p + (size_t)dl * (NE * FE));
        const float xa = xp[dl];
        a[0] += xa * w4.x; a[1] += xa * w4.y; a[2] += xa * w4.z; a[3] += xa * w4.w;
    }

    float* Vp = ws + VP_OFF + (size_t)(dc * 32 + e) * (16 * FE);
    *(float4*)(Vp + (rh * 8 + rw) * FE + f4 * 4) = make_float4(a[0], a[1], a[2], a[3]);
}

// ---------------------------------------------------------------------------
// K4: fused reduce + group-coupled relu + down-projection + atomic scatter.
// grid 512 = (rh 2)<<8 | (dt 8)<<5 | (e 32). Block: 8 rows x 128-d tile.
// Reduce covers exactly 8 rows x 32 f4 = 256 outputs = 1/thread (fixed OOB).
// ---------------------------------------------------------------------------
__global__ __launch_bounds__(256, 2)
void k_down(const float* __restrict__ f2, const float* __restrict__ bias,
            const float* __restrict__ ws, float* __restrict__ out)
{
    const int e   = blockIdx.x & 31;
    const int dt  = (blockIdx.x >> 5) & 7;     // 128-d output tile
    const int rh  = blockIdx.x >> 8;           // rows rh*8..+7 (2 full b-quads)
    const int tid = threadIdx.x;

    __shared__ float vv[8 * 132];
    __shared__ float hs[8 * 132];
    __shared__ int   gS[8];
    __shared__ float pS[8];

    if (tid < 8) {
        const int r = (rh * 8 + tid) * NE + e;
        gS[tid] = ((const int*)ws)[(size_t)r * NGRP];
        pS[tid] = ws[(size_t)r * NGRP + 1];
    }

    {   // reduce 16 K-chunk partials: one f4-output per thread (row*32+f4)
        const float* Vp = ws + VP_OFF;
        const int row = tid >> 5, f4 = tid & 31;
        float4 s = make_float4(0.f, 0.f, 0.f, 0.f);
#pragma unroll
        for (int dc = 0; dc < 16; ++dc) {
            const float4 v = *(const float4*)(Vp + (size_t)(dc * 32 + e) * (16 * FE)
                                                 + (rh * 8 + row) * FE + f4 * 4);
            s.x += v.x; s.y += v.y; s.z += v.z; s.w += v.w;
        }
        *(float4*)(vv + row * 132 + f4 * 4) = s;
    }
    __syncthreads();

    {   // group-coupled relu, p_t folded; quads are local rows {0..3},{4..7}
#pragma unroll
        for (int q = 0; q < 4; ++q) {
            const int idx = tid + q * 256;     // row*128 + f
            const int row = idx >> 7, f = idx & 127;
            const int qb = row & ~3;
            float u = bias[e * FE + f];
#pragma unroll
            for (int t2 = 0; t2 < T4; ++t2)
                if (gS[qb + t2] == gS[row]) u += pS[qb + t2] * vv[(qb + t2) * 132 + f];
            hs[row * 132 + f] = pS[row] * fmaxf(u, 0.f);
        }
    }
    __syncthreads();

    const int d4 = tid & 31;                   // 4 d's
    const int rw = tid >> 5;                   // local row 0..7
    const float* f2p = f2 + (size_t)e * FE * DM + dt * 128 + d4 * 4;
    const float* hp  = hs + rw * 132;

    float a[4] = {0.f, 0.f, 0.f, 0.f};
#pragma unroll 16
    for (int f = 0; f < FE; ++f) {
        const float4 w4 = *(const float4*)(f2p + (size_t)f * DM);
        const float ha = hp[f];
        a[0] += ha * w4.x; a[1] += ha * w4.y; a[2] += ha * w4.z; a[3] += ha * w4.w;
    }

    const int grow = rh * 8 + rw;
    const int bq = grow >> 2, t = grow & 3;
    float* orow = out + ((size_t)(bq * SS + gS[rw] * 4 + t)) * DM + dt * 128 + d4 * 4;
    atomicAdd(orow + 0, a[0]);
    atomicAdd(orow + 1, a[1]);
    atomicAdd(orow + 2, a[2]);
    atomicAdd(orow + 3, a[3]);
}

// ---------------------------------------------------------------------------
extern "C" void kernel_launch(void* const* d_in, const int* in_sizes, int n_in,
                              void* d_out, int out_size, void* d_ws, size_t ws_size,
                              hipStream_t stream)
{
    const float* x    = (const float*)d_in[0];
    const float* ctrl = (const float*)d_in[1];
    const float* f1   = (const float*)d_in[2];
    const float* bias = (const float*)d_in[3];
    const float* f2   = (const float*)d_in[4];
    float* out = (float*)d_out;
    float* ws  = (float*)d_ws;             // 8 MiB (Lp 4 splits; Vp aliases splits 1-2)

    k_logits<<<dim3(128, 4), 256, 0, stream>>>(x, ctrl, ws, out);
    k_route <<<dim3(512),     64, 0, stream>>>(ws);
    k_up    <<<dim3(1024),   256, 0, stream>>>(x, f1, ws);
    k_down  <<<dim3(512),    256, 0, stream>>>(f2, bias, ws, out);
}